// Round 13
// baseline (843.692 us; speedup 1.0000x reference)
//
#include <hip/hip_runtime.h>
#include <hip/hip_bf16.h>

constexpr float BN_EPS = 1e-5f;
typedef __attribute__((ext_vector_type(8))) short short8;
typedef __attribute__((ext_vector_type(4))) float f32x4;

// ---------------- hist (blocks 0..255) + weight prep (blocks 256..383) ----------------
// wt layout: wt[L*32768 + col*256 + ((((k&~7)*2) ^ ((col&7)<<4)) | ((k&7)*2))] (bytes)

__global__ void k_histprep(const int* __restrict__ dst, int* __restrict__ hist,
                           const float* __restrict__ Wh, char* __restrict__ wt,
                           int E, int B, int chunk) {
    int blk = blockIdx.x;
    if (blk >= 256) {
        int t = (blk - 256) * 256 + threadIdx.x;  // 0..32767
        int L = t >> 14;
        int rem = t & 16383;
        int k = rem >> 7, col = rem & 127;
        float v = Wh[(size_t)L * 16384 + k * 128 + col];
        int byte = L * 32768 + col * 256 + ((((k & ~7) * 2) ^ ((col & 7) << 4)) | ((k & 7) * 2));
        *(__hip_bfloat16*)(wt + byte) = __float2bfloat16(v);
        return;
    }
    __shared__ int lh[512];
    int t = threadIdx.x;
    for (int i = t; i < 512; i += 256) lh[i] = 0;
    __syncthreads();
    int e0 = blk * chunk, e1 = min(E, e0 + chunk);
    for (int e = e0 + t; e < e1; e += 256) {
        atomicAdd(&lh[dst[e] >> 8], 1);
    }
    __syncthreads();
    for (int b = t; b < B; b += 256) hist[b * 256 + blk] = lh[b];
}

// ---- generic exclusive scan ----

__global__ void g_scan1(const int* __restrict__ in, int* __restrict__ tsum,
                        int* __restrict__ bsum, int n, int ct) {
    int t = threadIdx.x, b = blockIdx.x;
    int i = b * 256 + t;
    int s0 = i * ct, s1 = min(n, s0 + ct);
    int s = 0;
    for (int k = s0; k < s1; ++k) s += in[k];
    tsum[i] = s;
    __shared__ int red[256];
    red[t] = s; __syncthreads();
    for (int d = 128; d > 0; d >>= 1) {
        if (t < d) red[t] += red[t + d];
        __syncthreads();
    }
    if (t == 0) bsum[b] = red[0];
}

__global__ void g_scan3(const int* __restrict__ in, const int* __restrict__ tsum,
                        const int* __restrict__ bsum, int* __restrict__ out,
                        int n, int ct) {
    int t = threadIdx.x, b = blockIdx.x;
    __shared__ int sh[256];
    __shared__ int bb[256];
    int bv = bsum[t];
    bb[t] = bv; __syncthreads();
    for (int d = 1; d < 256; d <<= 1) {
        int u = (t >= d) ? bb[t - d] : 0;
        __syncthreads();
        bb[t] += u;
        __syncthreads();
    }
    int v = tsum[b * 256 + t];
    sh[t] = v; __syncthreads();
    for (int d = 1; d < 256; d <<= 1) {
        int u = (t >= d) ? sh[t - d] : 0;
        __syncthreads();
        sh[t] += u;
        __syncthreads();
    }
    int bbase = bb[b] - bsum[b];
    int run = bbase + sh[t] - v;
    int i = b * 256 + t;
    int s0 = i * ct, s1 = min(n, s0 + ct);
    for (int k = s0; k < s1; ++k) {
        out[k] = run;
        run += in[k];
    }
    if (i == 65535) out[n] = bb[255];
}

__global__ void k_scatter(const int* __restrict__ src, const int* __restrict__ dst,
                          const int* __restrict__ sbase, unsigned int* __restrict__ pairs,
                          int E, int B, int chunk) {
    __shared__ int cur[512];
    int t = threadIdx.x, blk = blockIdx.x;
    for (int b = t; b < B; b += 256) cur[b] = sbase[b * 256 + blk];
    __syncthreads();
    int e0 = blk * chunk, e1 = min(E, e0 + chunk);
    for (int e = e0 + t; e < e1; e += 256) {
        int d = dst[e];
        int s = src[e];
        int p = atomicAdd(&cur[d >> 8], 1);
        pairs[p] = ((unsigned int)s << 8) | (unsigned int)(d & 255);
    }
}

__global__ void k_bucket(const unsigned int* __restrict__ pairs, const int* __restrict__ sbase,
                         const float* __restrict__ x, float* __restrict__ dinv,
                         float* __restrict__ xs, int* __restrict__ offs,
                         int* __restrict__ ss, int n) {
    __shared__ int sh[256];
    __shared__ int cur[256];
    int t = threadIdx.x, b = blockIdx.x;
    int p0 = sbase[b * 256];
    int p1 = sbase[b * 256 + 256];
    sh[t] = 0;
    __syncthreads();
    for (int p = p0 + t; p < p1; p += 256) {
        atomicAdd(&sh[pairs[p] & 255], 1);
    }
    __syncthreads();
    int cnt = sh[t];
    __syncthreads();
    sh[t] = cnt; __syncthreads();
    for (int d = 1; d < 256; d <<= 1) {
        int u = (t >= d) ? sh[t - d] : 0;
        __syncthreads();
        sh[t] += u;
        __syncthreads();
    }
    int excl = sh[t] - cnt;
    int node = b * 256 + t;
    if (node < n) {
        offs[node] = p0 + excl;
        if (node == n - 1) offs[n] = p0 + excl + cnt;
        float d = rsqrtf((float)(cnt + 1));  // +1 self loop
        dinv[node] = d;
        const float* xr = x + (size_t)node * 5;
        float* o = xs + (size_t)node * 8;
        #pragma unroll
        for (int j = 0; j < 5; ++j) o[j] = xr[j] * d;
        o[5] = 0.f; o[6] = 0.f; o[7] = 0.f;
    }
    cur[t] = p0 + excl;
    __syncthreads();
    for (int p = p0 + t; p < p1; p += 256) {
        unsigned int pk = pairs[p];
        int pos = atomicAdd(&cur[pk & 255], 1);
        ss[pos] = pk >> 8;
    }
}

// ---------------- layer 0 fused: agg5 + GEMM0 (+bias), bf16 out ----------------

__global__ __launch_bounds__(256) void k_layer0(const float* __restrict__ xs,
                                                const int* __restrict__ ss,
                                                const int* __restrict__ offs,
                                                const float* __restrict__ dinv,
                                                const float* __restrict__ W0,
                                                const float* __restrict__ bias0,
                                                unsigned int* __restrict__ h, int n) {
    __shared__ float xv[256 * 5];
    __shared__ float w[640];
    __shared__ float bsh[128];
    int t = threadIdx.x, blk = blockIdx.x;
    for (int i = t; i < 640; i += 256) w[i] = W0[i];
    if (t < 128) bsh[t] = bias0[t];

    int node = blk * 256 + t;
    float a0 = 0.f, a1 = 0.f, a2 = 0.f, a3 = 0.f, a4 = 0.f;
    if (node < n) {
        const float* xr = xs + (size_t)node * 8;
        a0 = xr[0]; a1 = xr[1]; a2 = xr[2]; a3 = xr[3]; a4 = xr[4];
        int e = offs[node], e1 = offs[node + 1];
        for (; e + 4 <= e1; e += 4) {
            int s0 = ss[e], s1 = ss[e + 1], s2 = ss[e + 2], s3 = ss[e + 3];
            float4 v0 = *(const float4*)(xs + (size_t)s0 * 8);
            float  w0 = xs[(size_t)s0 * 8 + 4];
            float4 v1 = *(const float4*)(xs + (size_t)s1 * 8);
            float  w1 = xs[(size_t)s1 * 8 + 4];
            float4 v2 = *(const float4*)(xs + (size_t)s2 * 8);
            float  w2 = xs[(size_t)s2 * 8 + 4];
            float4 v3 = *(const float4*)(xs + (size_t)s3 * 8);
            float  w3 = xs[(size_t)s3 * 8 + 4];
            a0 += v0.x + v1.x + v2.x + v3.x;
            a1 += v0.y + v1.y + v2.y + v3.y;
            a2 += v0.z + v1.z + v2.z + v3.z;
            a3 += v0.w + v1.w + v2.w + v3.w;
            a4 += w0 + w1 + w2 + w3;
        }
        for (; e < e1; ++e) {
            int s = ss[e];
            float4 v = *(const float4*)(xs + (size_t)s * 8);
            a0 += v.x; a1 += v.y; a2 += v.z; a3 += v.w; a4 += xs[(size_t)s * 8 + 4];
        }
        float dn = dinv[node];
        a0 *= dn; a1 *= dn; a2 *= dn; a3 *= dn; a4 *= dn;
    }
    float* xp = &xv[t * 5];
    xp[0] = a0; xp[1] = a1; xp[2] = a2; xp[3] = a3; xp[4] = a4;
    __syncthreads();

    int cp = t & 63, wgrp = t >> 6;
    int c0 = cp * 2, c1 = c0 + 1;
    float w00 = w[c0], w01 = w[128 + c0], w02 = w[256 + c0], w03 = w[384 + c0], w04 = w[512 + c0];
    float w10 = w[c1], w11 = w[128 + c1], w12 = w[256 + c1], w13 = w[384 + c1], w14 = w[512 + c1];
    float b0 = bsh[c0], b1 = bsh[c1];
    for (int i = 0; i < 64; ++i) {
        int ln = wgrp * 64 + i;
        int gnode = blk * 256 + ln;
        if (gnode < n) {
            const float* a = &xv[ln * 5];
            float r0 = b0 + a[0]*w00 + a[1]*w01 + a[2]*w02 + a[3]*w03 + a[4]*w04;
            float r1 = b1 + a[0]*w10 + a[1]*w11 + a[2]*w12 + a[3]*w13 + a[4]*w14;
            __hip_bfloat162 b2 = __float22bfloat162_rn(make_float2(r0, r1));
            h[(size_t)gnode * 64 + cp] = *reinterpret_cast<unsigned int*>(&b2);
        }
    }
}

// ---------------- BatchNorm stats: 64 blocks -> part[64][256] ----------------

__global__ void k_bnstats(const unsigned int* __restrict__ h2, float* __restrict__ part, int n) {
    __shared__ float4 red[256];
    int t = threadIdx.x, blk = blockIdx.x;
    int cp = t & 63, rg = t >> 6;
    float s0 = 0.f, s1 = 0.f, q0 = 0.f, q1 = 0.f;
    for (int r = blk * 4 + rg; r < n; r += 256) {
        unsigned int v = h2[(size_t)r * 64 + cp];
        float lo = __uint_as_float(v << 16);
        float hi = __uint_as_float(v & 0xffff0000u);
        s0 += lo; s1 += hi; q0 += lo * lo; q1 += hi * hi;
    }
    red[t] = make_float4(s0, s1, q0, q1);
    __syncthreads();
    if (t < 64) {
        float4 a = red[t], b = red[t + 64], c = red[t + 128], d = red[t + 192];
        float fs0 = a.x + b.x + c.x + d.x;
        float fs1 = a.y + b.y + c.y + d.y;
        float fq0 = a.z + b.z + c.z + d.z;
        float fq1 = a.w + b.w + c.w + d.w;
        float* p = part + blk * 256;
        p[2 * t] = fs0; p[2 * t + 1] = fs1;
        p[128 + 2 * t] = fq0; p[128 + 2 * t + 1] = fq1;
    }
}

// redundant per-block ab reduce: part[64][256] -> absh[256] (LDS). Call with all threads; syncs.
__device__ __forceinline__ void compute_ab(const float* __restrict__ part,
                                           const float* __restrict__ gamma,
                                           const float* __restrict__ beta,
                                           float* absh, int n, int t) {
    if (t < 128) {
        float s = 0.f, q = 0.f;
        #pragma unroll 8
        for (int b = 0; b < 64; ++b) {
            s += part[b * 256 + t];
            q += part[b * 256 + 128 + t];
        }
        float mean = s / n;
        float var = q / n - mean * mean;
        float inv = rsqrtf(var + BN_EPS);
        float A = gamma[t] * inv;
        absh[t] = A;
        absh[128 + t] = beta[t] - mean * A;
    }
    __syncthreads();
}

// ------- MFMA bf16 GEMM: bf16 A in, BN(ab from part)+ReLU fused on A-load,
//         pre-swizzled bf16 W^T, epilogue: scale by dinv[row], emit bf16 -------

__global__ __launch_bounds__(256) void k_gemm128(const unsigned int* __restrict__ A,
                                                 const char* __restrict__ wt,
                                                 const float* __restrict__ part,
                                                 const float* __restrict__ gamma,
                                                 const float* __restrict__ beta,
                                                 const float* __restrict__ dinv,
                                                 __hip_bfloat16* __restrict__ C, int n) {
    __shared__ uint4 AsU[2048];   // 32 KiB
    __shared__ uint4 WsU[2048];   // 32 KiB
    __shared__ float absh[256];
    char* Asb = (char*)AsU;
    char* Wsb = (char*)WsU;
    int tid = threadIdx.x;
    int row0 = blockIdx.x * 128;

    const uint4* wt4 = (const uint4*)wt;
    for (int i = tid; i < 2048; i += 256) WsU[i] = wt4[i];
    compute_ab(part, gamma, beta, absh, n, tid);  // syncs

    const float4* ab4 = (const float4*)absh;
    for (int g = tid; g < 2048; g += 256) {
        int r = g >> 4, kg = g & 15;
        int grow = row0 + r;
        uint4 pack = make_uint4(0, 0, 0, 0);
        if (grow < n) {
            uint4 raw = *(const uint4*)(A + (size_t)grow * 64 + kg * 4);
            float4 A0 = ab4[kg * 2], A1 = ab4[kg * 2 + 1];
            float4 B0 = ab4[32 + kg * 2], B1 = ab4[32 + kg * 2 + 1];
            float Af[8] = {A0.x, A0.y, A0.z, A0.w, A1.x, A1.y, A1.z, A1.w};
            float Bf[8] = {B0.x, B0.y, B0.z, B0.w, B1.x, B1.y, B1.z, B1.w};
            unsigned int* ru = (unsigned int*)&raw;
            unsigned int* pu = (unsigned int*)&pack;
            #pragma unroll
            for (int j = 0; j < 4; ++j) {
                unsigned int u = ru[j];
                float lo = __uint_as_float(u << 16);
                float hi = __uint_as_float(u & 0xffff0000u);
                float f0 = fmaxf(0.f, lo * Af[2 * j] + Bf[2 * j]);
                float f1 = fmaxf(0.f, hi * Af[2 * j + 1] + Bf[2 * j + 1]);
                __hip_bfloat162 b2 = __float22bfloat162_rn(make_float2(f0, f1));
                pu[j] = *reinterpret_cast<unsigned int*>(&b2);
            }
        }
        int byte = r * 256 + ((kg << 4) ^ ((r & 7) << 4));
        *(uint4*)(Asb + byte) = pack;
    }
    __syncthreads();

    int wv_ = tid >> 6, lane = tid & 63;
    int wr = wv_ * 32;
    int lrow = lane & 15, lk = lane >> 4;
    f32x4 acc[2][8];
    #pragma unroll
    for (int m = 0; m < 2; ++m)
        #pragma unroll
        for (int nf = 0; nf < 8; ++nf) acc[m][nf] = (f32x4)(0.f);

    #pragma unroll
    for (int kk = 0; kk < 4; ++kk) {
        int k0 = kk * 32 + lk * 8;
        int ra = wr + lrow;
        int rb = wr + 16 + lrow;
        short8 a0 = *(short8*)(Asb + ra * 256 + ((k0 * 2) ^ ((ra & 7) << 4)));
        short8 a1 = *(short8*)(Asb + rb * 256 + ((k0 * 2) ^ ((rb & 7) << 4)));
        #pragma unroll
        for (int nf = 0; nf < 8; ++nf) {
            int col = nf * 16 + lrow;
            short8 b = *(short8*)(Wsb + col * 256 + ((k0 * 2) ^ ((col & 7) << 4)));
            acc[0][nf] = __builtin_amdgcn_mfma_f32_16x16x32_bf16(a0, b, acc[0][nf], 0, 0, 0);
            acc[1][nf] = __builtin_amdgcn_mfma_f32_16x16x32_bf16(a1, b, acc[1][nf], 0, 0, 0);
        }
    }

    #pragma unroll
    for (int m = 0; m < 2; ++m) {
        #pragma unroll
        for (int r = 0; r < 4; ++r) {
            int grow = row0 + wr + m * 16 + lk * 4 + r;
            if (grow < n) {
                float dv = dinv[grow];
                __hip_bfloat16* crow = C + (size_t)grow * 128 + lrow;
                #pragma unroll
                for (int nf = 0; nf < 8; ++nf) {
                    crow[nf * 16] = __float2bfloat16(acc[m][nf][r] * dv);
                }
            }
        }
    }
}

// ---------------- 128-ch aggregation: one wave per node, bf16 in/out, 8x unroll ----------------
// gsum0 non-null on the last layer: first 16 blocks zero it (pool runs later)

__global__ void k_agg128(const unsigned int* __restrict__ hb, const int* __restrict__ ss,
                         const int* __restrict__ offs, const float* __restrict__ dinv,
                         const float* __restrict__ bias, unsigned int* __restrict__ hout,
                         float* __restrict__ gsum0, int n) {
    if (gsum0 && blockIdx.x < 16) {
        for (int i = threadIdx.x; i < 512; i += 256) gsum0[blockIdx.x * 512 + i] = 0.f;
    }
    int wid = threadIdx.x >> 6, lane = threadIdx.x & 63;
    int node = blockIdx.x * (blockDim.x >> 6) + wid;
    if (node >= n) return;
    unsigned int self = hb[(size_t)node * 64 + lane];
    float ax = __uint_as_float(self << 16);
    float ay = __uint_as_float(self & 0xffff0000u);
    int e = offs[node], e1 = offs[node + 1];
    for (; e + 8 <= e1; e += 8) {
        int s0 = ss[e], s1 = ss[e+1], s2 = ss[e+2], s3 = ss[e+3];
        int s4 = ss[e+4], s5 = ss[e+5], s6 = ss[e+6], s7 = ss[e+7];
        unsigned int v0 = hb[(size_t)s0 * 64 + lane];
        unsigned int v1 = hb[(size_t)s1 * 64 + lane];
        unsigned int v2 = hb[(size_t)s2 * 64 + lane];
        unsigned int v3 = hb[(size_t)s3 * 64 + lane];
        unsigned int v4 = hb[(size_t)s4 * 64 + lane];
        unsigned int v5 = hb[(size_t)s5 * 64 + lane];
        unsigned int v6 = hb[(size_t)s6 * 64 + lane];
        unsigned int v7 = hb[(size_t)s7 * 64 + lane];
        ax += __uint_as_float(v0 << 16); ay += __uint_as_float(v0 & 0xffff0000u);
        ax += __uint_as_float(v1 << 16); ay += __uint_as_float(v1 & 0xffff0000u);
        ax += __uint_as_float(v2 << 16); ay += __uint_as_float(v2 & 0xffff0000u);
        ax += __uint_as_float(v3 << 16); ay += __uint_as_float(v3 & 0xffff0000u);
        ax += __uint_as_float(v4 << 16); ay += __uint_as_float(v4 & 0xffff0000u);
        ax += __uint_as_float(v5 << 16); ay += __uint_as_float(v5 & 0xffff0000u);
        ax += __uint_as_float(v6 << 16); ay += __uint_as_float(v6 & 0xffff0000u);
        ax += __uint_as_float(v7 << 16); ay += __uint_as_float(v7 & 0xffff0000u);
    }
    for (; e + 4 <= e1; e += 4) {
        int s0 = ss[e], s1 = ss[e+1], s2 = ss[e+2], s3 = ss[e+3];
        unsigned int v0 = hb[(size_t)s0 * 64 + lane];
        unsigned int v1 = hb[(size_t)s1 * 64 + lane];
        unsigned int v2 = hb[(size_t)s2 * 64 + lane];
        unsigned int v3 = hb[(size_t)s3 * 64 + lane];
        ax += __uint_as_float(v0 << 16); ay += __uint_as_float(v0 & 0xffff0000u);
        ax += __uint_as_float(v1 << 16); ay += __uint_as_float(v1 & 0xffff0000u);
        ax += __uint_as_float(v2 << 16); ay += __uint_as_float(v2 & 0xffff0000u);
        ax += __uint_as_float(v3 << 16); ay += __uint_as_float(v3 & 0xffff0000u);
    }
    for (; e < e1; ++e) {
        unsigned int v = hb[(size_t)ss[e] * 64 + lane];
        ax += __uint_as_float(v << 16);
        ay += __uint_as_float(v & 0xffff0000u);
    }
    float dn = dinv[node];
    float2 b = ((const float2*)bias)[lane];
    float ox = ax * dn + b.x;
    float oy = ay * dn + b.y;
    __hip_bfloat162 b2 = __float22bfloat162_rn(make_float2(ox, oy));
    hout[(size_t)node * 64 + lane] = *reinterpret_cast<unsigned int*>(&b2);
}

// ---------------- pooling (BN ab computed in-kernel) + head ----------------

__global__ void k_pool(const unsigned int* __restrict__ h2, const int* __restrict__ batch,
                       const float* __restrict__ part, const float* __restrict__ gamma,
                       const float* __restrict__ beta, float* __restrict__ gsum,
                       int n, int rows_per_block) {
    __shared__ float absh[256];
    int tid = threadIdx.x;
    compute_ab(part, gamma, beta, absh, n, tid);  // syncs
    int cp = tid & 63, rg = tid >> 6;
    int c0 = cp * 2, c1 = c0 + 1;
    int r0 = blockIdx.x * rows_per_block;
    int r1 = min(r0 + rows_per_block, n);
    int qlen = rows_per_block >> 2;
    int rs = r0 + rg * qlen;
    int re = min(rs + qlen, r1);
    float A0 = absh[c0], B0 = absh[128 + c0];
    float A1 = absh[c1], B1 = absh[128 + c1];
    float a0 = 0.f, a1 = 0.f; int cur = -1;
    for (int r = rs; r < re; ++r) {
        int g = batch[r];
        if (g != cur) {
            if (cur >= 0) {
                atomicAdd(&gsum[cur * 128 + c0], a0);
                atomicAdd(&gsum[cur * 128 + c1], a1);
            }
            a0 = 0.f; a1 = 0.f; cur = g;
        }
        unsigned int v = h2[(size_t)r * 64 + cp];
        float lo = __uint_as_float(v << 16);
        float hi = __uint_as_float(v & 0xffff0000u);
        a0 += fmaxf(0.f, lo * A0 + B0);
        a1 += fmaxf(0.f, hi * A1 + B1);
    }
    if (cur >= 0) {
        atomicAdd(&gsum[cur * 128 + c0], a0);
        atomicAdd(&gsum[cur * 128 + c1], a1);
    }
}

__global__ void k_final(const float* __restrict__ gsum, const int* __restrict__ batch,
                        const float* __restrict__ embW, const float* __restrict__ embb,
                        float* __restrict__ out, int n) {
    __shared__ float row[128];
    __shared__ int bnd[2];
    int g = blockIdx.x, j = threadIdx.x;  // 64 threads
    if (j < 2) {
        int target = g + j;
        int lo = 0, hi = n;
        while (lo < hi) {
            int mid = (lo + hi) >> 1;
            if (batch[mid] < target) lo = mid + 1; else hi = mid;
        }
        bnd[j] = lo;
    }
    __syncthreads();
    float cnt = (float)(bnd[1] - bnd[0]);
    float invc = 1.f / fmaxf(cnt, 1.f);
    for (int i = j; i < 128; i += 64) row[i] = gsum[g * 128 + i] * invc;
    __syncthreads();
    float acc = embb[j];
    for (int cdx = 0; cdx < 128; ++cdx) acc += row[cdx] * embW[cdx * 64 + j];
    out[g * 64 + j] = acc;
}

// ---------------- launch ----------------

extern "C" void kernel_launch(void* const* d_in, const int* in_sizes, int n_in,
                              void* d_out, int out_size, void* d_ws, size_t ws_size,
                              hipStream_t stream) {
    const float* x     = (const float*)d_in[0];
    const float* W0    = (const float*)d_in[1];
    const float* Wh    = (const float*)d_in[2];
    const float* bias  = (const float*)d_in[3];
    const float* gamma = (const float*)d_in[4];
    const float* beta  = (const float*)d_in[5];
    const float* embW  = (const float*)d_in[6];
    const float* embb  = (const float*)d_in[7];
    const int*   ei    = (const int*)d_in[8];
    const int*   batch = (const int*)d_in[9];
    int N = in_sizes[9];
    int E = in_sizes[8] / 2;
    const int* src = ei;
    const int* dst = ei + E;
    int B = (N + 255) >> 8;

    char* w = (char*)d_ws;
    size_t off = 0;
    auto carve = [&](size_t bytes) {
        char* p = w + off;
        off = (off + bytes + 255) & ~(size_t)255;
        return (void*)p;
    };
    float* dinv   = (float*)carve((size_t)N * 4);
    int*   offs   = (int*)carve((size_t)(N + 1) * 4);
    int*   ss     = (int*)carve((size_t)E * 4);
    unsigned int* pairs = (unsigned int*)carve((size_t)E * 4);
    int*   hist   = (int*)carve((size_t)B * 256 * 4);
    int*   sbase  = (int*)carve(((size_t)B * 256 + 1) * 4);
    float* xs     = (float*)carve((size_t)N * 8 * 4);
    unsigned int* hA = (unsigned int*)carve((size_t)N * 128 * 2);
    __hip_bfloat16* hB = (__hip_bfloat16*)carve((size_t)N * 128 * 2);
    char*  wt     = (char*)carve(2 * 32768);
    float* part   = (float*)carve(64 * 256 * 4);
    float* gsum   = (float*)carve(64 * 128 * 4);
    int*   tsum   = (int*)carve(65536 * 4);
    int*   bsum   = (int*)carve(256 * 4);
    (void)ws_size; (void)n_in; (void)out_size;

    int nb = (N + 255) / 256;
    int gb = (N + 127) / 128;
    int ab4 = (N + 3) / 4;
    int echunk = (E + 255) / 256;
    int nH = B * 256;
    int ctH = (nH + 65535) / 65536;

    // graph prep (+ weight prep fused)
    k_histprep<<<384, 256, 0, stream>>>(dst, hist, Wh, wt, E, B, echunk);
    g_scan1<<<256, 256, 0, stream>>>(hist, tsum, bsum, nH, ctH);
    g_scan3<<<256, 256, 0, stream>>>(hist, tsum, bsum, sbase, nH, ctH);
    k_scatter<<<256, 256, 0, stream>>>(src, dst, sbase, pairs, E, B, echunk);
    k_bucket<<<B, 256, 0, stream>>>(pairs, sbase, x, dinv, xs, offs, ss, N);

    // layer 0
    k_layer0<<<nb, 256, 0, stream>>>(xs, ss, offs, dinv, W0, bias, hA, N);
    k_bnstats<<<64, 256, 0, stream>>>(hA, part, N);

    // layer 1 (gemm computes ab from part internally)
    k_gemm128<<<gb, 256, 0, stream>>>(hA, wt, part, gamma, beta, dinv, hB, N);
    k_agg128<<<ab4, 256, 0, stream>>>((const unsigned int*)hB, ss, offs, dinv, bias + 128, hA, nullptr, N);
    k_bnstats<<<64, 256, 0, stream>>>(hA, part, N);

    // layer 2 (last agg zeroes gsum)
    k_gemm128<<<gb, 256, 0, stream>>>(hA, wt + 32768, part, gamma + 128, beta + 128, dinv, hB, N);
    k_agg128<<<ab4, 256, 0, stream>>>((const unsigned int*)hB, ss, offs, dinv, bias + 256, hA, gsum, N);
    k_bnstats<<<64, 256, 0, stream>>>(hA, part, N);

    // pool (computes ab internally, fuses BN+ReLU) + head
    int rpb = 512;
    k_pool<<<(N + rpb - 1) / rpb, 256, 0, stream>>>(hA, batch, part, gamma + 256, beta + 256, gsum, N, rpb);
    k_final<<<64, 64, 0, stream>>>(gsum, batch, embW, embb, (float*)d_out, N);
}

// Round 14
// 525.832 us; speedup vs baseline: 1.6045x; 1.6045x over previous
//
#include <hip/hip_runtime.h>
#include <hip/hip_bf16.h>

constexpr float BN_EPS = 1e-5f;
typedef __attribute__((ext_vector_type(8))) short short8;
typedef __attribute__((ext_vector_type(4))) float f32x4;

// ---------------- hist (blocks 0..255) + weight prep (blocks 256..383) ----------------
// wt layout: wt[L*32768 + col*256 + ((((k&~7)*2) ^ ((col&7)<<4)) | ((k&7)*2))] (bytes)

__global__ void k_histprep(const int* __restrict__ dst, int* __restrict__ hist,
                           const float* __restrict__ Wh, char* __restrict__ wt,
                           int E, int B, int chunk) {
    int blk = blockIdx.x;
    if (blk >= 256) {
        int t = (blk - 256) * 256 + threadIdx.x;  // 0..32767
        int L = t >> 14;
        int rem = t & 16383;
        int k = rem >> 7, col = rem & 127;
        float v = Wh[(size_t)L * 16384 + k * 128 + col];
        int byte = L * 32768 + col * 256 + ((((k & ~7) * 2) ^ ((col & 7) << 4)) | ((k & 7) * 2));
        *(__hip_bfloat16*)(wt + byte) = __float2bfloat16(v);
        return;
    }
    __shared__ int lh[512];
    int t = threadIdx.x;
    for (int i = t; i < 512; i += 256) lh[i] = 0;
    __syncthreads();
    int e0 = blk * chunk, e1 = min(E, e0 + chunk);
    for (int e = e0 + t; e < e1; e += 256) {
        atomicAdd(&lh[dst[e] >> 8], 1);
    }
    __syncthreads();
    for (int b = t; b < B; b += 256) hist[b * 256 + blk] = lh[b];
}

// ---- generic exclusive scan ----

__global__ void g_scan1(const int* __restrict__ in, int* __restrict__ tsum,
                        int* __restrict__ bsum, int n, int ct) {
    int t = threadIdx.x, b = blockIdx.x;
    int i = b * 256 + t;
    int s0 = i * ct, s1 = min(n, s0 + ct);
    int s = 0;
    for (int k = s0; k < s1; ++k) s += in[k];
    tsum[i] = s;
    __shared__ int red[256];
    red[t] = s; __syncthreads();
    for (int d = 128; d > 0; d >>= 1) {
        if (t < d) red[t] += red[t + d];
        __syncthreads();
    }
    if (t == 0) bsum[b] = red[0];
}

__global__ void g_scan3(const int* __restrict__ in, const int* __restrict__ tsum,
                        const int* __restrict__ bsum, int* __restrict__ out,
                        int n, int ct) {
    int t = threadIdx.x, b = blockIdx.x;
    __shared__ int sh[256];
    __shared__ int bb[256];
    int bv = bsum[t];
    bb[t] = bv; __syncthreads();
    for (int d = 1; d < 256; d <<= 1) {
        int u = (t >= d) ? bb[t - d] : 0;
        __syncthreads();
        bb[t] += u;
        __syncthreads();
    }
    int v = tsum[b * 256 + t];
    sh[t] = v; __syncthreads();
    for (int d = 1; d < 256; d <<= 1) {
        int u = (t >= d) ? sh[t - d] : 0;
        __syncthreads();
        sh[t] += u;
        __syncthreads();
    }
    int bbase = bb[b] - bsum[b];
    int run = bbase + sh[t] - v;
    int i = b * 256 + t;
    int s0 = i * ct, s1 = min(n, s0 + ct);
    for (int k = s0; k < s1; ++k) {
        out[k] = run;
        run += in[k];
    }
    if (i == 65535) out[n] = bb[255];
}

__global__ void k_scatter(const int* __restrict__ src, const int* __restrict__ dst,
                          const int* __restrict__ sbase, unsigned int* __restrict__ pairs,
                          int E, int B, int chunk) {
    __shared__ int cur[512];
    int t = threadIdx.x, blk = blockIdx.x;
    for (int b = t; b < B; b += 256) cur[b] = sbase[b * 256 + blk];
    __syncthreads();
    int e0 = blk * chunk, e1 = min(E, e0 + chunk);
    for (int e = e0 + t; e < e1; e += 256) {
        int d = dst[e];
        int s = src[e];
        int p = atomicAdd(&cur[d >> 8], 1);
        pairs[p] = ((unsigned int)s << 8) | (unsigned int)(d & 255);
    }
}

// per-bucket CSR build; also zeroes partA (first 16 blocks)
__global__ void k_bucket(const unsigned int* __restrict__ pairs, const int* __restrict__ sbase,
                         const float* __restrict__ x, float* __restrict__ dinv,
                         float* __restrict__ xs, int* __restrict__ offs,
                         int* __restrict__ ss, float* __restrict__ part_zero, int n) {
    __shared__ int sh[256];
    __shared__ int cur[256];
    int t = threadIdx.x, b = blockIdx.x;
    if (b < 16) {
        for (int i = t; i < 1024; i += 256) part_zero[b * 1024 + i] = 0.f;
    }
    int p0 = sbase[b * 256];
    int p1 = sbase[b * 256 + 256];
    sh[t] = 0;
    __syncthreads();
    for (int p = p0 + t; p < p1; p += 256) {
        atomicAdd(&sh[pairs[p] & 255], 1);
    }
    __syncthreads();
    int cnt = sh[t];
    __syncthreads();
    sh[t] = cnt; __syncthreads();
    for (int d = 1; d < 256; d <<= 1) {
        int u = (t >= d) ? sh[t - d] : 0;
        __syncthreads();
        sh[t] += u;
        __syncthreads();
    }
    int excl = sh[t] - cnt;
    int node = b * 256 + t;
    if (node < n) {
        offs[node] = p0 + excl;
        if (node == n - 1) offs[n] = p0 + excl + cnt;
        float d = rsqrtf((float)(cnt + 1));  // +1 self loop
        dinv[node] = d;
        const float* xr = x + (size_t)node * 5;
        float* o = xs + (size_t)node * 8;
        #pragma unroll
        for (int j = 0; j < 5; ++j) o[j] = xr[j] * d;
        o[5] = 0.f; o[6] = 0.f; o[7] = 0.f;
    }
    cur[t] = p0 + excl;
    __syncthreads();
    for (int p = p0 + t; p < p1; p += 256) {
        unsigned int pk = pairs[p];
        int pos = atomicAdd(&cur[pk & 255], 1);
        ss[pos] = pk >> 8;
    }
}

// ---------------- layer 0 fused: agg5 + GEMM0 (+bias), bf16 out, BN stats -> partA ----------------
// also zeroes partB (first 16 blocks)

__global__ __launch_bounds__(256) void k_layer0(const float* __restrict__ xs,
                                                const int* __restrict__ ss,
                                                const int* __restrict__ offs,
                                                const float* __restrict__ dinv,
                                                const float* __restrict__ W0,
                                                const float* __restrict__ bias0,
                                                unsigned int* __restrict__ h,
                                                float* __restrict__ part_out,
                                                float* __restrict__ part_zero, int n) {
    __shared__ float xv[256 * 5];
    __shared__ float w[640];
    __shared__ float bsh[128];
    __shared__ float4 red[256];
    int t = threadIdx.x, blk = blockIdx.x;
    if (blk < 16) {
        for (int i = t; i < 1024; i += 256) part_zero[blk * 1024 + i] = 0.f;
    }
    for (int i = t; i < 640; i += 256) w[i] = W0[i];
    if (t < 128) bsh[t] = bias0[t];

    int node = blk * 256 + t;
    float a0 = 0.f, a1 = 0.f, a2 = 0.f, a3 = 0.f, a4 = 0.f;
    if (node < n) {
        const float* xr = xs + (size_t)node * 8;
        a0 = xr[0]; a1 = xr[1]; a2 = xr[2]; a3 = xr[3]; a4 = xr[4];
        int e = offs[node], e1 = offs[node + 1];
        for (; e + 8 <= e1; e += 8) {
            int si[8];
            #pragma unroll
            for (int j = 0; j < 8; ++j) si[j] = ss[e + j];
            float4 v[8]; float w4[8];
            #pragma unroll
            for (int j = 0; j < 8; ++j) {
                v[j] = *(const float4*)(xs + (size_t)si[j] * 8);
                w4[j] = xs[(size_t)si[j] * 8 + 4];
            }
            #pragma unroll
            for (int j = 0; j < 8; ++j) {
                a0 += v[j].x; a1 += v[j].y; a2 += v[j].z; a3 += v[j].w; a4 += w4[j];
            }
        }
        for (; e < e1; ++e) {
            int s = ss[e];
            float4 v = *(const float4*)(xs + (size_t)s * 8);
            a0 += v.x; a1 += v.y; a2 += v.z; a3 += v.w; a4 += xs[(size_t)s * 8 + 4];
        }
        float dn = dinv[node];
        a0 *= dn; a1 *= dn; a2 *= dn; a3 *= dn; a4 *= dn;
    }
    float* xp = &xv[t * 5];
    xp[0] = a0; xp[1] = a1; xp[2] = a2; xp[3] = a3; xp[4] = a4;
    __syncthreads();

    int cp = t & 63, wgrp = t >> 6;
    int c0 = cp * 2, c1 = c0 + 1;
    float w00 = w[c0], w01 = w[128 + c0], w02 = w[256 + c0], w03 = w[384 + c0], w04 = w[512 + c0];
    float w10 = w[c1], w11 = w[128 + c1], w12 = w[256 + c1], w13 = w[384 + c1], w14 = w[512 + c1];
    float b0 = bsh[c0], b1 = bsh[c1];
    float S0 = 0.f, S1 = 0.f, Q0 = 0.f, Q1 = 0.f;
    for (int i = 0; i < 64; ++i) {
        int ln = wgrp * 64 + i;
        int gnode = blk * 256 + ln;
        if (gnode < n) {
            const float* a = &xv[ln * 5];
            float r0 = b0 + a[0]*w00 + a[1]*w01 + a[2]*w02 + a[3]*w03 + a[4]*w04;
            float r1 = b1 + a[0]*w10 + a[1]*w11 + a[2]*w12 + a[3]*w13 + a[4]*w14;
            S0 += r0; S1 += r1; Q0 += r0 * r0; Q1 += r1 * r1;
            __hip_bfloat162 b2 = __float22bfloat162_rn(make_float2(r0, r1));
            h[(size_t)gnode * 64 + cp] = *reinterpret_cast<unsigned int*>(&b2);
        }
    }
    __syncthreads();
    red[t] = make_float4(S0, S1, Q0, Q1);
    __syncthreads();
    if (t < 64) {
        float4 a = red[t], b = red[t + 64], c = red[t + 128], d = red[t + 192];
        float* p = part_out + (blk & 63) * 256;
        atomicAdd(&p[2 * t],       a.x + b.x + c.x + d.x);
        atomicAdd(&p[2 * t + 1],   a.y + b.y + c.y + d.y);
        atomicAdd(&p[128 + 2 * t],     a.z + b.z + c.z + d.z);
        atomicAdd(&p[128 + 2 * t + 1], a.w + b.w + c.w + d.w);
    }
}

// redundant per-block ab reduce: part[64][256] -> absh[256] (LDS). Call with all threads; syncs.
__device__ __forceinline__ void compute_ab(const float* __restrict__ part,
                                           const float* __restrict__ gamma,
                                           const float* __restrict__ beta,
                                           float* absh, int n, int t) {
    if (t < 128) {
        float s = 0.f, q = 0.f;
        #pragma unroll 8
        for (int b = 0; b < 64; ++b) {
            s += part[b * 256 + t];
            q += part[b * 256 + 128 + t];
        }
        float mean = s / n;
        float var = q / n - mean * mean;
        float inv = rsqrtf(var + BN_EPS);
        float A = gamma[t] * inv;
        absh[t] = A;
        absh[128 + t] = beta[t] - mean * A;
    }
    __syncthreads();
}

// ------- MFMA bf16 GEMM: bf16 A in, BN(ab from part)+ReLU fused on A-load,
//         pre-swizzled bf16 W^T, epilogue: scale by dinv[row], emit bf16 -------

__global__ __launch_bounds__(256) void k_gemm128(const unsigned int* __restrict__ A,
                                                 const char* __restrict__ wt,
                                                 const float* __restrict__ part,
                                                 const float* __restrict__ gamma,
                                                 const float* __restrict__ beta,
                                                 const float* __restrict__ dinv,
                                                 __hip_bfloat16* __restrict__ C, int n) {
    __shared__ uint4 AsU[2048];   // 32 KiB
    __shared__ uint4 WsU[2048];   // 32 KiB
    __shared__ float absh[256];
    char* Asb = (char*)AsU;
    char* Wsb = (char*)WsU;
    int tid = threadIdx.x;
    int row0 = blockIdx.x * 128;

    const uint4* wt4 = (const uint4*)wt;
    for (int i = tid; i < 2048; i += 256) WsU[i] = wt4[i];
    compute_ab(part, gamma, beta, absh, n, tid);  // syncs

    const float4* ab4 = (const float4*)absh;
    for (int g = tid; g < 2048; g += 256) {
        int r = g >> 4, kg = g & 15;
        int grow = row0 + r;
        uint4 pack = make_uint4(0, 0, 0, 0);
        if (grow < n) {
            uint4 raw = *(const uint4*)(A + (size_t)grow * 64 + kg * 4);
            float4 A0 = ab4[kg * 2], A1 = ab4[kg * 2 + 1];
            float4 B0 = ab4[32 + kg * 2], B1 = ab4[32 + kg * 2 + 1];
            float Af[8] = {A0.x, A0.y, A0.z, A0.w, A1.x, A1.y, A1.z, A1.w};
            float Bf[8] = {B0.x, B0.y, B0.z, B0.w, B1.x, B1.y, B1.z, B1.w};
            unsigned int* ru = (unsigned int*)&raw;
            unsigned int* pu = (unsigned int*)&pack;
            #pragma unroll
            for (int j = 0; j < 4; ++j) {
                unsigned int u = ru[j];
                float lo = __uint_as_float(u << 16);
                float hi = __uint_as_float(u & 0xffff0000u);
                float f0 = fmaxf(0.f, lo * Af[2 * j] + Bf[2 * j]);
                float f1 = fmaxf(0.f, hi * Af[2 * j + 1] + Bf[2 * j + 1]);
                __hip_bfloat162 b2 = __float22bfloat162_rn(make_float2(f0, f1));
                pu[j] = *reinterpret_cast<unsigned int*>(&b2);
            }
        }
        int byte = r * 256 + ((kg << 4) ^ ((r & 7) << 4));
        *(uint4*)(Asb + byte) = pack;
    }
    __syncthreads();

    int wv_ = tid >> 6, lane = tid & 63;
    int wr = wv_ * 32;
    int lrow = lane & 15, lk = lane >> 4;
    f32x4 acc[2][8];
    #pragma unroll
    for (int m = 0; m < 2; ++m)
        #pragma unroll
        for (int nf = 0; nf < 8; ++nf) acc[m][nf] = (f32x4)(0.f);

    #pragma unroll
    for (int kk = 0; kk < 4; ++kk) {
        int k0 = kk * 32 + lk * 8;
        int ra = wr + lrow;
        int rb = wr + 16 + lrow;
        short8 a0 = *(short8*)(Asb + ra * 256 + ((k0 * 2) ^ ((ra & 7) << 4)));
        short8 a1 = *(short8*)(Asb + rb * 256 + ((k0 * 2) ^ ((rb & 7) << 4)));
        #pragma unroll
        for (int nf = 0; nf < 8; ++nf) {
            int col = nf * 16 + lrow;
            short8 b = *(short8*)(Wsb + col * 256 + ((k0 * 2) ^ ((col & 7) << 4)));
            acc[0][nf] = __builtin_amdgcn_mfma_f32_16x16x32_bf16(a0, b, acc[0][nf], 0, 0, 0);
            acc[1][nf] = __builtin_amdgcn_mfma_f32_16x16x32_bf16(a1, b, acc[1][nf], 0, 0, 0);
        }
    }

    #pragma unroll
    for (int m = 0; m < 2; ++m) {
        #pragma unroll
        for (int r = 0; r < 4; ++r) {
            int grow = row0 + wr + m * 16 + lk * 4 + r;
            if (grow < n) {
                float dv = dinv[grow];
                __hip_bfloat16* crow = C + (size_t)grow * 128 + lrow;
                #pragma unroll
                for (int nf = 0; nf < 8; ++nf) {
                    crow[nf * 16] = __float2bfloat16(acc[m][nf][r] * dv);
                }
            }
        }
    }
}

// ---------------- 128-ch aggregation: wave-per-node, 64 nodes/block, bf16 in/out,
//                  16x unroll, BN stats -> part_out; optional zero of part_zero/gsum0 --------

__global__ __launch_bounds__(256) void k_agg128(const unsigned int* __restrict__ hb,
                                                const int* __restrict__ ss,
                                                const int* __restrict__ offs,
                                                const float* __restrict__ dinv,
                                                const float* __restrict__ bias,
                                                unsigned int* __restrict__ hout,
                                                float* __restrict__ part_out,
                                                float* __restrict__ part_zero,
                                                float* __restrict__ gsum0, int n) {
    __shared__ float4 red[256];
    int tid = threadIdx.x;
    int wid = tid >> 6, lane = tid & 63;
    if (part_zero && blockIdx.x < 16) {
        for (int i = tid; i < 1024; i += 256) part_zero[blockIdx.x * 1024 + i] = 0.f;
    }
    if (gsum0 && blockIdx.x < 16) {
        for (int i = tid; i < 512; i += 256) gsum0[blockIdx.x * 512 + i] = 0.f;
    }
    float2 b = ((const float2*)bias)[lane];
    float S0 = 0.f, S1 = 0.f, Q0 = 0.f, Q1 = 0.f;
    int base = blockIdx.x * 64 + wid * 16;
    for (int ni = 0; ni < 16; ++ni) {
        int node = base + ni;
        if (node >= n) break;
        unsigned int self = hb[(size_t)node * 64 + lane];
        float ax = __uint_as_float(self << 16);
        float ay = __uint_as_float(self & 0xffff0000u);
        int e = offs[node], e1 = offs[node + 1];
        for (; e + 16 <= e1; e += 16) {
            int si[16];
            #pragma unroll
            for (int j = 0; j < 16; ++j) si[j] = ss[e + j];
            unsigned int v[16];
            #pragma unroll
            for (int j = 0; j < 16; ++j) v[j] = hb[(size_t)si[j] * 64 + lane];
            #pragma unroll
            for (int j = 0; j < 16; ++j) {
                ax += __uint_as_float(v[j] << 16);
                ay += __uint_as_float(v[j] & 0xffff0000u);
            }
        }
        for (; e + 4 <= e1; e += 4) {
            int si[4];
            #pragma unroll
            for (int j = 0; j < 4; ++j) si[j] = ss[e + j];
            unsigned int v[4];
            #pragma unroll
            for (int j = 0; j < 4; ++j) v[j] = hb[(size_t)si[j] * 64 + lane];
            #pragma unroll
            for (int j = 0; j < 4; ++j) {
                ax += __uint_as_float(v[j] << 16);
                ay += __uint_as_float(v[j] & 0xffff0000u);
            }
        }
        for (; e < e1; ++e) {
            unsigned int v = hb[(size_t)ss[e] * 64 + lane];
            ax += __uint_as_float(v << 16);
            ay += __uint_as_float(v & 0xffff0000u);
        }
        float dn = dinv[node];
        float ox = ax * dn + b.x;
        float oy = ay * dn + b.y;
        S0 += ox; S1 += oy; Q0 += ox * ox; Q1 += oy * oy;
        __hip_bfloat162 b2 = __float22bfloat162_rn(make_float2(ox, oy));
        hout[(size_t)node * 64 + lane] = *reinterpret_cast<unsigned int*>(&b2);
    }
    red[tid] = make_float4(S0, S1, Q0, Q1);
    __syncthreads();
    if (tid < 64) {
        float4 a = red[tid], c = red[tid + 64], d = red[tid + 128], e4 = red[tid + 192];
        float* p = part_out + (blockIdx.x & 63) * 256;
        atomicAdd(&p[2 * tid],       a.x + c.x + d.x + e4.x);
        atomicAdd(&p[2 * tid + 1],   a.y + c.y + d.y + e4.y);
        atomicAdd(&p[128 + 2 * tid],     a.z + c.z + d.z + e4.z);
        atomicAdd(&p[128 + 2 * tid + 1], a.w + c.w + d.w + e4.w);
    }
}

// ---------------- pooling (BN ab computed in-kernel) + head ----------------

__global__ void k_pool(const unsigned int* __restrict__ h2, const int* __restrict__ batch,
                       const float* __restrict__ part, const float* __restrict__ gamma,
                       const float* __restrict__ beta, float* __restrict__ gsum,
                       int n, int rows_per_block) {
    __shared__ float absh[256];
    int tid = threadIdx.x;
    compute_ab(part, gamma, beta, absh, n, tid);  // syncs
    int cp = tid & 63, rg = tid >> 6;
    int c0 = cp * 2, c1 = c0 + 1;
    int r0 = blockIdx.x * rows_per_block;
    int r1 = min(r0 + rows_per_block, n);
    int qlen = rows_per_block >> 2;
    int rs = r0 + rg * qlen;
    int re = min(rs + qlen, r1);
    float A0 = absh[c0], B0 = absh[128 + c0];
    float A1 = absh[c1], B1 = absh[128 + c1];
    float a0 = 0.f, a1 = 0.f; int cur = -1;
    for (int r = rs; r < re; ++r) {
        int g = batch[r];
        if (g != cur) {
            if (cur >= 0) {
                atomicAdd(&gsum[cur * 128 + c0], a0);
                atomicAdd(&gsum[cur * 128 + c1], a1);
            }
            a0 = 0.f; a1 = 0.f; cur = g;
        }
        unsigned int v = h2[(size_t)r * 64 + cp];
        float lo = __uint_as_float(v << 16);
        float hi = __uint_as_float(v & 0xffff0000u);
        a0 += fmaxf(0.f, lo * A0 + B0);
        a1 += fmaxf(0.f, hi * A1 + B1);
    }
    if (cur >= 0) {
        atomicAdd(&gsum[cur * 128 + c0], a0);
        atomicAdd(&gsum[cur * 128 + c1], a1);
    }
}

__global__ void k_final(const float* __restrict__ gsum, const int* __restrict__ batch,
                        const float* __restrict__ embW, const float* __restrict__ embb,
                        float* __restrict__ out, int n) {
    __shared__ float row[128];
    __shared__ int bnd[2];
    int g = blockIdx.x, j = threadIdx.x;  // 64 threads
    if (j < 2) {
        int target = g + j;
        int lo = 0, hi = n;
        while (lo < hi) {
            int mid = (lo + hi) >> 1;
            if (batch[mid] < target) lo = mid + 1; else hi = mid;
        }
        bnd[j] = lo;
    }
    __syncthreads();
    float cnt = (float)(bnd[1] - bnd[0]);
    float invc = 1.f / fmaxf(cnt, 1.f);
    for (int i = j; i < 128; i += 64) row[i] = gsum[g * 128 + i] * invc;
    __syncthreads();
    float acc = embb[j];
    for (int cdx = 0; cdx < 128; ++cdx) acc += row[cdx] * embW[cdx * 64 + j];
    out[g * 64 + j] = acc;
}

// ---------------- launch ----------------

extern "C" void kernel_launch(void* const* d_in, const int* in_sizes, int n_in,
                              void* d_out, int out_size, void* d_ws, size_t ws_size,
                              hipStream_t stream) {
    const float* x     = (const float*)d_in[0];
    const float* W0    = (const float*)d_in[1];
    const float* Wh    = (const float*)d_in[2];
    const float* bias  = (const float*)d_in[3];
    const float* gamma = (const float*)d_in[4];
    const float* beta  = (const float*)d_in[5];
    const float* embW  = (const float*)d_in[6];
    const float* embb  = (const float*)d_in[7];
    const int*   ei    = (const int*)d_in[8];
    const int*   batch = (const int*)d_in[9];
    int N = in_sizes[9];
    int E = in_sizes[8] / 2;
    const int* src = ei;
    const int* dst = ei + E;
    int B = (N + 255) >> 8;

    char* w = (char*)d_ws;
    size_t off = 0;
    auto carve = [&](size_t bytes) {
        char* p = w + off;
        off = (off + bytes + 255) & ~(size_t)255;
        return (void*)p;
    };
    float* dinv   = (float*)carve((size_t)N * 4);
    int*   offs   = (int*)carve((size_t)(N + 1) * 4);
    int*   ss     = (int*)carve((size_t)E * 4);
    unsigned int* pairs = (unsigned int*)carve((size_t)E * 4);
    int*   hist   = (int*)carve((size_t)B * 256 * 4);
    int*   sbase  = (int*)carve(((size_t)B * 256 + 1) * 4);
    float* xs     = (float*)carve((size_t)N * 8 * 4);
    unsigned int* hA = (unsigned int*)carve((size_t)N * 128 * 2);
    __hip_bfloat16* hB = (__hip_bfloat16*)carve((size_t)N * 128 * 2);
    char*  wt     = (char*)carve(2 * 32768);
    float* partA  = (float*)carve(64 * 256 * 4);
    float* partB  = (float*)carve(64 * 256 * 4);
    float* gsum   = (float*)carve(64 * 128 * 4);
    int*   tsum   = (int*)carve(65536 * 4);
    int*   bsum   = (int*)carve(256 * 4);
    (void)ws_size; (void)n_in; (void)out_size;

    int nb = (N + 255) / 256;
    int gb = (N + 127) / 128;
    int ab64 = (N + 63) / 64;
    int echunk = (E + 255) / 256;
    int nH = B * 256;
    int ctH = (nH + 65535) / 65536;

    // graph prep (+ weight prep fused)
    k_histprep<<<384, 256, 0, stream>>>(dst, hist, Wh, wt, E, B, echunk);
    g_scan1<<<256, 256, 0, stream>>>(hist, tsum, bsum, nH, ctH);
    g_scan3<<<256, 256, 0, stream>>>(hist, tsum, bsum, sbase, nH, ctH);
    k_scatter<<<256, 256, 0, stream>>>(src, dst, sbase, pairs, E, B, echunk);
    k_bucket<<<B, 256, 0, stream>>>(pairs, sbase, x, dinv, xs, offs, ss, partA, N);  // zeroes partA

    // layer 0 (fused agg5+gemm0; stats -> partA; zeroes partB)
    k_layer0<<<nb, 256, 0, stream>>>(xs, ss, offs, dinv, W0, bias, hA, partA, partB, N);

    // layer 1 (gemm: ab from partA; agg: stats -> partB, zeroes partA)
    k_gemm128<<<gb, 256, 0, stream>>>(hA, wt, partA, gamma, beta, dinv, hB, N);
    k_agg128<<<ab64, 256, 0, stream>>>((const unsigned int*)hB, ss, offs, dinv, bias + 128,
                                       hA, partB, partA, nullptr, N);

    // layer 2 (gemm: ab from partB; agg: stats -> partA, zeroes gsum)
    k_gemm128<<<gb, 256, 0, stream>>>(hA, wt + 32768, partB, gamma + 128, beta + 128, dinv, hB, N);
    k_agg128<<<ab64, 256, 0, stream>>>((const unsigned int*)hB, ss, offs, dinv, bias + 256,
                                       hA, partA, nullptr, gsum, N);

    // pool (ab from partA, fuses BN+ReLU) + head
    int rpb = 256;
    k_pool<<<(N + rpb - 1) / rpb, 256, 0, stream>>>(hA, batch, partA, gamma + 256, beta + 256, gsum, N, rpb);
    k_final<<<64, 64, 0, stream>>>(gsum, batch, embW, embb, (float*)d_out, N);
}